// Round 7
// baseline (149.491 us; speedup 1.0000x reference)
//
#include <hip/hip_runtime.h>
#include <hip/hip_bf16.h>

typedef __attribute__((ext_vector_type(4))) float f32x4;
typedef __attribute__((ext_vector_type(8))) short s16x8;
typedef __attribute__((ext_vector_type(4))) short s16x4;

__device__ __forceinline__ unsigned short f2bf(float f) {
    unsigned int u; __builtin_memcpy(&u, &f, 4);
    u += 0x7fffu + ((u >> 16) & 1u);
    return (unsigned short)(u >> 16);
}
__device__ __forceinline__ float bf2f(unsigned short h) {
    unsigned int u = ((unsigned int)h) << 16;
    float f; __builtin_memcpy(&f, &u, 4);
    return f;
}
__device__ __forceinline__ s16x8 pack8(f32x4 a, f32x4 b) {
    s16x8 r;
    r[0] = (short)f2bf(a[0]); r[1] = (short)f2bf(a[1]);
    r[2] = (short)f2bf(a[2]); r[3] = (short)f2bf(a[3]);
    r[4] = (short)f2bf(b[0]); r[5] = (short)f2bf(b[1]);
    r[6] = (short)f2bf(b[2]); r[7] = (short)f2bf(b[3]);
    return r;
}

// ---------------------------------------------------------------------------
// Generic C = A @ B^T (+bias) GEMM, K=256 — small matmuls (agent proj, chain).
// Each block handles one 64-col tile (nt = blockIdx.y) of 128 rows.
// ---------------------------------------------------------------------------
template<bool AF32, bool BF32, bool OUTBF16, bool BIAS>
__global__ __launch_bounds__(256) void gemm_k256(
    const void* __restrict__ Ap, long sA, long bAstr,
    const void* __restrict__ Bp, long sB,
    const float* __restrict__ bias,
    void* __restrict__ Cp, long sC, long bCstr,
    int M, int N)
{
    __shared__ alignas(16) unsigned short As[128 * 256];
    __shared__ alignas(16) unsigned short Bs[64 * 256];
    const int tid = threadIdx.x;
    const int lane = tid & 63;
    const int w = tid >> 6;
    const int m0 = blockIdx.x * 128;
    const int nt = blockIdx.y;
    const int z = blockIdx.z;

    {
        const int kk = (tid & 31) * 8;
        #pragma unroll
        for (int j = 0; j < 16; ++j) {
            const int row = (tid >> 5) + j * 8;
            int rowg = m0 + row; if (rowg > M - 1) rowg = M - 1;
            s16x8 v;
            if constexpr (AF32) {
                const float* s = (const float*)Ap + (size_t)z * bAstr + (size_t)rowg * sA + kk;
                f32x4 f0 = *(const f32x4*)s;
                f32x4 f1 = *(const f32x4*)(s + 4);
                v = pack8(f0, f1);
            } else {
                const unsigned short* s = (const unsigned short*)Ap + (size_t)z * bAstr + (size_t)rowg * sA + kk;
                v = *(const s16x8*)s;
            }
            *(s16x8*)((char*)As + row * 512 + ((kk * 2) ^ ((row & 7) << 4))) = v;
        }
        #pragma unroll
        for (int j = 0; j < 8; ++j) {
            const int row = (tid >> 5) + j * 8;
            const int rowg = nt * 64 + row;
            s16x8 v;
            if constexpr (BF32) {
                const float* s = (const float*)Bp + (size_t)rowg * sB + kk;
                f32x4 f0 = *(const f32x4*)s;
                f32x4 f1 = *(const f32x4*)(s + 4);
                v = pack8(f0, f1);
            } else {
                const unsigned short* s = (const unsigned short*)Bp + (size_t)rowg * sB + kk;
                v = *(const s16x8*)s;
            }
            *(s16x8*)((char*)Bs + row * 512 + ((kk * 2) ^ ((row & 7) << 4))) = v;
        }
    }
    __syncthreads();

    f32x4 acc[2][4];
    const f32x4 zero = {0.f, 0.f, 0.f, 0.f};
    #pragma unroll
    for (int rf = 0; rf < 2; ++rf)
        #pragma unroll
        for (int cf = 0; cf < 4; ++cf)
            acc[rf][cf] = zero;

    #pragma unroll
    for (int ks = 0; ks < 8; ++ks) {
        const int kb = ks * 64 + ((lane >> 4) << 4);
        s16x8 areg[2], bfr[4];
        #pragma unroll
        for (int rf = 0; rf < 2; ++rf) {
            const int row = w * 32 + rf * 16 + (lane & 15);
            areg[rf] = *(const s16x8*)((const char*)As + row * 512 + (kb ^ ((row & 7) << 4)));
        }
        #pragma unroll
        for (int cf = 0; cf < 4; ++cf) {
            const int row = cf * 16 + (lane & 15);
            bfr[cf] = *(const s16x8*)((const char*)Bs + row * 512 + (kb ^ ((row & 7) << 4)));
        }
        #pragma unroll
        for (int rf = 0; rf < 2; ++rf)
            #pragma unroll
            for (int cf = 0; cf < 4; ++cf)
                acc[rf][cf] = __builtin_amdgcn_mfma_f32_16x16x32_bf16(
                    areg[rf], bfr[cf], acc[rf][cf], 0, 0, 0);
    }

    #pragma unroll
    for (int cf = 0; cf < 4; ++cf) {
        const int n = nt * 64 + cf * 16 + (lane & 15);
        const float bv = BIAS ? bias[n] : 0.f;
        #pragma unroll
        for (int rf = 0; rf < 2; ++rf) {
            #pragma unroll
            for (int r = 0; r < 4; ++r) {
                const int m = m0 + w * 32 + rf * 16 + ((lane >> 4) << 2) + r;
                if (m < M) {
                    const float v = acc[rf][cf][r] + bv;
                    const size_t co = (size_t)z * bCstr + (size_t)m * sC + n;
                    if constexpr (OUTBF16) ((unsigned short*)Cp)[co] = f2bf(v);
                    else                   ((float*)Cp)[co] = v;
                }
            }
        }
    }
}

// ---------------------------------------------------------------------------
// Build MS [128][256] bf16 + cbias[128]:
//   rows  0..63 : M1[a] = qa_s @ W_k  (cbias = b_k . qa_s[a])   [stage-1]
//   rows 64..127: M2[a] = ka_s @ W_q  (cbias = b_q . ka_s[a])   [stage-2]
// ---------------------------------------------------------------------------
__global__ __launch_bounds__(256) void build_M2(
    const float* __restrict__ W_qkv, const float* __restrict__ b_qkv,
    const float* __restrict__ qa_out,
    unsigned short* __restrict__ MS, float* __restrict__ cbias)
{
    const int i = blockIdx.x;  // 0..127
    const int t = threadIdx.x;
    __shared__ float qs[256];
    const int a = i & 63;
    const bool isS1 = (i < 64);
    qs[t] = qa_out[(size_t)a * 512 + (isS1 ? t : 256 + t)] * 0.0625f;
    __syncthreads();
    const float* W  = W_qkv + (isS1 ? 256 * 256 : 0);   // W_k : W_q
    const float* bb = b_qkv + (isS1 ? 256 : 0);
    float acc = 0.f, cb = 0.f;
    for (int dout = 0; dout < 256; ++dout) {
        const float q = qs[dout];
        acc += q * W[(size_t)dout * 256 + t];
        cb  += q * bb[dout];
    }
    MS[i * 256 + t] = f2bf(acc);
    if (t == 0) cbias[i] = cb;
}

// ---------------------------------------------------------------------------
// Streaming scores.  Per 64-token block:
//   S1T[n][a] f32 + stage-1 softmax partials (global softmax over n later);
//   P2[n][a]  bf16 = FINALIZED stage-2 softmax probs (pre-swizzled rows).
// S2 MFMA is wave-local in tokens (wave w owns rows w*16..w*16+15, all 64
// agent cols) so the 64-agent softmax needs only in-thread + 4-shfl reduces.
// ---------------------------------------------------------------------------
__global__ __launch_bounds__(256) void xproj2(
    const float* __restrict__ x,
    const unsigned short* __restrict__ MS,
    const float* __restrict__ cbias,
    float* __restrict__ S1T,
    unsigned short* __restrict__ P2,
    float* __restrict__ mpart, float* __restrict__ lpart)
{
    __shared__ alignas(16) unsigned short As[64 * 256];   // 32KB
    const int tid = threadIdx.x, lane = tid & 63, w = tid >> 6;
    const int lr = lane & 15, lq = lane >> 4;
    const long m0 = (long)blockIdx.x * 64;

    {
        const int k0 = (tid & 31) * 8;
        #pragma unroll
        for (int j = 0; j < 8; ++j) {
            const int row = (tid >> 5) + j * 8;
            const float* s = x + (m0 + row) * 256 + k0;
            f32x4 f0 = *(const f32x4*)s;
            f32x4 f1 = *(const f32x4*)(s + 4);
            *(s16x8*)((char*)As + row * 512 + ((k0 * 2) ^ ((row & 7) << 4))) = pack8(f0, f1);
        }
    }
    __syncthreads();

    f32x4 acc0[4];   // S1: token row-frags rf (all 64 tokens), agents w*16+lr
    f32x4 acc1[4];   // S2: token rows w*16.., agent col-frags cf*16+lr
    const f32x4 zero = {0.f, 0.f, 0.f, 0.f};
    #pragma unroll
    for (int i = 0; i < 4; ++i) { acc0[i] = zero; acc1[i] = zero; }

    const int roww = w * 16 + lr;   // this wave's token row for S2 A-frag
    #pragma unroll
    for (int ks = 0; ks < 8; ++ks) {
        const int kb = ks * 64 + lq * 16;
        s16x8 areg[4];
        #pragma unroll
        for (int rf = 0; rf < 4; ++rf) {
            const int row = rf * 16 + lr;
            areg[rf] = *(const s16x8*)((const char*)As + row * 512 + (kb ^ ((row & 7) << 4)));
        }
        // S1: B-frag = this wave's 16 agents (MS rows 0..63)
        s16x8 b0 = *(const s16x8*)((const char*)MS + (size_t)(w * 16 + lr) * 512 + kb);
        #pragma unroll
        for (int rf = 0; rf < 4; ++rf)
            acc0[rf] = __builtin_amdgcn_mfma_f32_16x16x32_bf16(areg[rf], b0, acc0[rf], 0, 0, 0);
        // S2: A-frag = wave's own token rows; B-frags = all 64 agents (MS 64..127)
        s16x8 aw = *(const s16x8*)((const char*)As + roww * 512 + (kb ^ ((roww & 7) << 4)));
        s16x8 b1[4];
        #pragma unroll
        for (int cf = 0; cf < 4; ++cf)
            b1[cf] = *(const s16x8*)((const char*)MS + (size_t)(64 + cf * 16 + lr) * 512 + kb);
        #pragma unroll
        for (int cf = 0; cf < 4; ++cf)
            acc1[cf] = __builtin_amdgcn_mfma_f32_16x16x32_bf16(aw, b1[cf], acc1[cf], 0, 0, 0);
    }

    // ---- S1 epilogue: write scores f32 + per-block softmax partials ----
    {
        const int a = w * 16 + lr;
        const float bv = cbias[a];
        float mx = -1e30f;
        #pragma unroll
        for (int rf = 0; rf < 4; ++rf)
            #pragma unroll
            for (int r = 0; r < 4; ++r) {
                const float v = acc0[rf][r] + bv;
                S1T[(m0 + rf * 16 + lq * 4 + r) * 64 + a] = v;
                mx = fmaxf(mx, v);
            }
        mx = fmaxf(mx, __shfl_xor(mx, 16));
        mx = fmaxf(mx, __shfl_xor(mx, 32));
        float sm = 0.f;
        #pragma unroll
        for (int rf = 0; rf < 4; ++rf)
            #pragma unroll
            for (int r = 0; r < 4; ++r)
                sm += __expf(acc0[rf][r] + bv - mx);
        sm += __shfl_xor(sm, 16);
        sm += __shfl_xor(sm, 32);
        if (lq == 0) {
            mpart[(size_t)blockIdx.x * 64 + a] = mx;
            lpart[(size_t)blockIdx.x * 64 + a] = sm;
        }
    }

    // ---- S2 epilogue: finalize softmax per token, write P2 bf16 swizzled ----
    {
        float bv1[4];
        #pragma unroll
        for (int cf = 0; cf < 4; ++cf) bv1[cf] = cbias[64 + cf * 16 + lr];
        #pragma unroll
        for (int r = 0; r < 4; ++r) {
            float v[4];
            #pragma unroll
            for (int cf = 0; cf < 4; ++cf) v[cf] = acc1[cf][r] + bv1[cf];
            float m = fmaxf(fmaxf(v[0], v[1]), fmaxf(v[2], v[3]));
            m = fmaxf(m, __shfl_xor(m, 1));
            m = fmaxf(m, __shfl_xor(m, 2));
            m = fmaxf(m, __shfl_xor(m, 4));
            m = fmaxf(m, __shfl_xor(m, 8));
            float p[4], s = 0.f;
            #pragma unroll
            for (int cf = 0; cf < 4; ++cf) { p[cf] = __expf(v[cf] - m); s += p[cf]; }
            s += __shfl_xor(s, 1);
            s += __shfl_xor(s, 2);
            s += __shfl_xor(s, 4);
            s += __shfl_xor(s, 8);
            const float rs = 1.f / s;
            const int nl = w * 16 + lq * 4 + r;
            const int swz = (nl & 7) << 4;
            char* row = (char*)P2 + (m0 + nl) * 128;
            #pragma unroll
            for (int cf = 0; cf < 4; ++cf)
                *(unsigned short*)(row + ((2 * (cf * 16 + lr)) ^ swz)) = f2bf(p[cf] * rs);
        }
    }
}

// ---------------------------------------------------------------------------
// Combine stage-1 partials (128 chunks of 64 tokens per batch).
// ---------------------------------------------------------------------------
__global__ __launch_bounds__(256) void s1_combine(const float* __restrict__ mpart,
                                                  const float* __restrict__ lpart,
                                                  float* __restrict__ m1,
                                                  float* __restrict__ l1inv)
{
    const int b = blockIdx.x;
    const int a = threadIdx.x & 63, s = threadIdx.x >> 6;
    float M = -1e30f;
    for (int c = s; c < 128; c += 4)
        M = fmaxf(M, mpart[((size_t)b * 128 + c) * 64 + a]);
    float L = 0.f;
    for (int c = s; c < 128; c += 4) {
        const size_t idx = ((size_t)b * 128 + c) * 64 + a;
        L += lpart[idx] * __expf(mpart[idx] - M);
    }
    __shared__ float ms[256], ls[256];
    ms[threadIdx.x] = M; ls[threadIdx.x] = L;
    __syncthreads();
    if (threadIdx.x < 64) {
        const int aa = threadIdx.x;
        float Mm = ms[aa];
        #pragma unroll
        for (int ss = 1; ss < 4; ++ss) Mm = fmaxf(Mm, ms[ss * 64 + aa]);
        float Ll = 0.f;
        #pragma unroll
        for (int ss = 0; ss < 4; ++ss) Ll += ls[ss * 64 + aa] * __expf(ms[ss * 64 + aa] - Mm);
        m1[b * 64 + aa] = Mm;
        l1inv[b * 64 + aa] = 1.0f / Ll;
    }
}

// ---------------------------------------------------------------------------
// y = attn1 @ x via MFMA (partials over 32 n-chunks of 256).
// ---------------------------------------------------------------------------
__global__ __launch_bounds__(256) void pv_mfma2(
    const float* __restrict__ S1T,
    const float* __restrict__ x,
    const float* __restrict__ m1,
    const float* __restrict__ l1inv,
    float* __restrict__ y_part)
{
    __shared__ alignas(16) unsigned short P_lds[64 * 128];   // [a][n] 16KB
    __shared__ alignas(16) unsigned short XT[128 * 136];     // [d][136n] (pad row)
    const int tid = threadIdx.x, lane = tid & 63, w = tid >> 6;
    const int lr = lane & 15, lq = lane >> 4;
    const int c = blockIdx.x, dh = blockIdx.y, b = blockIdx.z;

    const int a4 = (tid & 15) * 4;
    const f32x4 m4 = *(const f32x4*)&m1[b * 64 + a4];
    const f32x4 l4 = *(const f32x4*)&l1inv[b * 64 + a4];

    f32x4 acc[4][2];
    const f32x4 zero = {0.f, 0.f, 0.f, 0.f};
    #pragma unroll
    for (int rf = 0; rf < 4; ++rf)
        #pragma unroll
        for (int cf = 0; cf < 2; ++cf)
            acc[rf][cf] = zero;

    for (int kt = 0; kt < 2; ++kt) {
        const size_t ng0 = (size_t)b * 8192 + c * 256 + kt * 128;
        #pragma unroll
        for (int pass = 0; pass < 4; ++pass) {
            const int np = 2 * (tid >> 4) + pass * 32;
            const float* s = S1T + (ng0 + np) * 64 + a4;
            f32x4 s0 = *(const f32x4*)s;
            f32x4 s1 = *(const f32x4*)(s + 64);
            #pragma unroll
            for (int j = 0; j < 4; ++j) {
                const int a = a4 + j;
                const float p0 = __expf(s0[j] - m4[j]) * l4[j];
                const float p1 = __expf(s1[j] - m4[j]) * l4[j];
                const unsigned int pk = (unsigned int)f2bf(p0) | ((unsigned int)f2bf(p1) << 16);
                *(unsigned int*)((char*)P_lds + a * 256 + ((np * 2) ^ (((a >> 1) & 7) << 4))) = pk;
            }
        }
        {
            const int nh = tid >> 2;
            const int dq = tid & 3;
            const float* xbase = x + (ng0 + 2 * nh) * 256 + dh * 128;
            #pragma unroll
            for (int pass = 0; pass < 8; ++pass) {
                const int dl0 = pass * 16 + dq * 4;
                f32x4 xa = *(const f32x4*)(xbase + dl0);
                f32x4 xb = *(const f32x4*)(xbase + 256 + dl0);
                #pragma unroll
                for (int jj = 0; jj < 4; ++jj) {
                    const unsigned int pk = (unsigned int)f2bf(xa[jj]) | ((unsigned int)f2bf(xb[jj]) << 16);
                    *(unsigned int*)((char*)XT + (dl0 + jj) * 272 + nh * 4) = pk;
                }
            }
        }
        __syncthreads();
        #pragma unroll
        for (int ks = 0; ks < 4; ++ks) {
            const int kbn = ks * 64 + lq * 16;
            s16x8 af[4], bfv[2];
            #pragma unroll
            for (int rf = 0; rf < 4; ++rf) {
                const int row = rf * 16 + lr;
                af[rf] = *(const s16x8*)((const char*)P_lds + row * 256 + (kbn ^ (((row >> 1) & 7) << 4)));
            }
            #pragma unroll
            for (int cf = 0; cf < 2; ++cf) {
                const int dl = w * 32 + cf * 16 + lr;
                bfv[cf] = *(const s16x8*)((const char*)XT + dl * 272 + kbn);
            }
            #pragma unroll
            for (int rf = 0; rf < 4; ++rf)
                #pragma unroll
                for (int cf = 0; cf < 2; ++cf)
                    acc[rf][cf] = __builtin_amdgcn_mfma_f32_16x16x32_bf16(
                        af[rf], bfv[cf], acc[rf][cf], 0, 0, 0);
        }
        __syncthreads();
    }
    #pragma unroll
    for (int rf = 0; rf < 4; ++rf)
        #pragma unroll
        for (int cf = 0; cf < 2; ++cf)
            #pragma unroll
            for (int r = 0; r < 4; ++r) {
                const int a = rf * 16 + lq * 4 + r;
                const int d = dh * 128 + w * 32 + cf * 16 + lr;
                y_part[(((size_t)b * 32 + c) * 64 + a) * 256 + d] = acc[rf][cf][r];
            }
}

__global__ void v1_reduce(const float* __restrict__ y_part,
                          float* __restrict__ y_raw)
{
    const int a = blockIdx.x, b = blockIdx.y, t = threadIdx.x;  // 64 thr
    f32x4 s = {0.f, 0.f, 0.f, 0.f};
    for (int c = 0; c < 32; ++c)
        s += *(const f32x4*)&y_part[(((size_t)b * 32 + c) * 64 + a) * 256 + t * 4];
    *(f32x4*)&y_raw[((size_t)b * 64 + a) * 256 + t * 4] = s;
}

// ---------------------------------------------------------------------------
// Stage-2 fused: P2 (finalized bf16 probs, pre-swizzled) copy -> LDS, PV via
// MFMA (A = uT rows d, B = P rows n), residual + RMSNorm, f32x4 hot path.
// ---------------------------------------------------------------------------
__global__ __launch_bounds__(256) void stage2_final(const unsigned short* __restrict__ P2,
                                                    const float* __restrict__ uu,
                                                    const float* __restrict__ x,
                                                    const float* __restrict__ nscale,
                                                    float* __restrict__ out)
{
    __shared__ alignas(16) unsigned short uT[256 * 64];  // [d][a] pitch 128B, swz
    __shared__ alignas(16) unsigned short P[64 * 64];    // [n][a] pitch 128B, swz
    __shared__ float ssq[4][64];
    const int tid = threadIdx.x, lane = tid & 63, w = tid >> 6;
    const int lr = lane & 15, lq = lane >> 4;
    const int b = blockIdx.x >> 7;
    const long n0 = (long)blockIdx.x * 64;

    // ---- stage uT[d][a] bf16 from uu[b][a][d] f32 (pair-packed transpose) ----
    {
        const int pr = tid >> 3;      // a-pair 0..31
        const int sub = tid & 7;
        const float* u0 = uu + ((size_t)b * 64 + 2 * pr) * 256;
        #pragma unroll
        for (int pass = 0; pass < 8; ++pass) {
            const int d0 = pass * 32 + sub * 4;
            f32x4 ua = *(const f32x4*)(u0 + d0);
            f32x4 ub = *(const f32x4*)(u0 + 256 + d0);
            #pragma unroll
            for (int jj = 0; jj < 4; ++jj) {
                const int d = d0 + jj;
                const unsigned int pk = (unsigned int)f2bf(ua[jj]) | ((unsigned int)f2bf(ub[jj]) << 16);
                *(unsigned int*)((char*)uT + d * 128 + ((pr * 4) ^ ((d & 7) << 4))) = pk;
            }
        }
    }
    // ---- stage P: verbatim copy (global rows already swizzled) ----
    {
        const int row = tid & 63, seg = tid >> 6;   // 4 segs x 32B
        const char* src = (const char*)P2 + (n0 + row) * 128 + seg * 32;
        s16x8 v0 = *(const s16x8*)src;
        s16x8 v1 = *(const s16x8*)(src + 16);
        *(s16x8*)((char*)P + row * 128 + seg * 32) = v0;
        *(s16x8*)((char*)P + row * 128 + seg * 32 + 16) = v1;
    }
    __syncthreads();

    // ---- PV MFMA: A = uT rows (d), B = P rows (n) -> C[d][n] ----
    f32x4 acc[4][4];
    const f32x4 zero = {0.f, 0.f, 0.f, 0.f};
    #pragma unroll
    for (int rf = 0; rf < 4; ++rf)
        #pragma unroll
        for (int cf = 0; cf < 4; ++cf)
            acc[rf][cf] = zero;
    #pragma unroll
    for (int ks = 0; ks < 2; ++ks) {
        const int kb = ks * 64 + lq * 16;
        s16x8 af[4], bfv[4];
        #pragma unroll
        for (int rf = 0; rf < 4; ++rf) {
            const int dR = w * 64 + rf * 16 + lr;
            af[rf] = *(const s16x8*)((const char*)uT + dR * 128 + (kb ^ ((dR & 7) << 4)));
        }
        #pragma unroll
        for (int cf = 0; cf < 4; ++cf) {
            const int nR = cf * 16 + lr;
            bfv[cf] = *(const s16x8*)((const char*)P + nR * 128 + (kb ^ ((nR & 7) << 4)));
        }
        #pragma unroll
        for (int rf = 0; rf < 4; ++rf)
            #pragma unroll
            for (int cf = 0; cf < 4; ++cf)
                acc[rf][cf] = __builtin_amdgcn_mfma_f32_16x16x32_bf16(
                    af[rf], bfv[cf], acc[rf][cf], 0, 0, 0);
    }

    // ---- residual (f32x4) + per-token partial ssq ----
    float part[4] = {0.f, 0.f, 0.f, 0.f};
    #pragma unroll
    for (int cf = 0; cf < 4; ++cf) {
        const long n = n0 + cf * 16 + lr;
        #pragma unroll
        for (int rf = 0; rf < 4; ++rf) {
            const int d0 = w * 64 + rf * 16 + lq * 4;
            const f32x4 xr = *(const f32x4*)&x[n * 256 + d0];
            acc[rf][cf] += xr;
            part[cf] += acc[rf][cf][0] * acc[rf][cf][0] + acc[rf][cf][1] * acc[rf][cf][1]
                      + acc[rf][cf][2] * acc[rf][cf][2] + acc[rf][cf][3] * acc[rf][cf][3];
        }
    }
    #pragma unroll
    for (int cf = 0; cf < 4; ++cf) {
        float s = part[cf];
        s += __shfl_xor(s, 16);
        s += __shfl_xor(s, 32);
        if (lq == 0) ssq[w][cf * 16 + lr] = s;
    }
    __syncthreads();

    // ---- rmsnorm + store (f32x4) ----
    #pragma unroll
    for (int cf = 0; cf < 4; ++cf) {
        const int tokl = cf * 16 + lr;
        const float tot = ssq[0][tokl] + ssq[1][tokl] + ssq[2][tokl] + ssq[3][tokl];
        const float inv = 1.f / (sqrtf(tot) * 0.0625f + 1e-8f);
        const long n = n0 + tokl;
        #pragma unroll
        for (int rf = 0; rf < 4; ++rf) {
            const int d0 = w * 64 + rf * 16 + lq * 4;
            const f32x4 sc4 = *(const f32x4*)&nscale[d0];
            f32x4 o = sc4 * acc[rf][cf] * inv;
            *(f32x4*)&out[n * 256 + d0] = o;
        }
    }
}

// ---------------------------------------------------------------------------
extern "C" void kernel_launch(void* const* d_in, const int* in_sizes, int n_in,
                              void* d_out, int out_size, void* d_ws, size_t ws_size,
                              hipStream_t stream)
{
    const float* agent   = (const float*)d_in[0];
    const float* x       = (const float*)d_in[1];
    const float* W_qkv   = (const float*)d_in[2];
    const float* b_qkv   = (const float*)d_in[3];
    const float* W_agent = (const float*)d_in[4];
    const float* b_agent = (const float*)d_in[5];
    const float* W_fc1   = (const float*)d_in[6];
    const float* b_fc1   = (const float*)d_in[7];
    const float* W_fc2   = (const float*)d_in[8];
    const float* b_fc2   = (const float*)d_in[9];
    const float* nscale  = (const float*)d_in[10];
    float* out = (float*)d_out;

    char* wsp = (char*)d_ws;
    size_t off = 0;
    auto alloc = [&](size_t n) { void* p = wsp + off; off += (n + 255) & ~(size_t)255; return p; };

    float*  qa_out = (float*)alloc(64UL * 512 * 4);
    unsigned short* MS = (unsigned short*)alloc(128UL * 256 * 2);
    float*  cbias  = (float*)alloc(128UL * 4);
    float*  S1T    = (float*)alloc(65536UL * 64 * 4);            // [n][a] f32
    unsigned short* P2 = (unsigned short*)alloc(65536UL * 64 * 2); // [n][a] bf16 swz
    float*  mpart  = (float*)alloc(1024UL * 64 * 4);
    float*  lpart  = (float*)alloc(1024UL * 64 * 4);
    float*  m1     = (float*)alloc(512UL * 4);
    float*  l1inv  = (float*)alloc(512UL * 4);
    float*  y_part = (float*)alloc(8UL * 32 * 64 * 256 * 4);
    float*  y_raw  = (float*)alloc(512UL * 256 * 4);
    float*  t0     = (float*)alloc(512UL * 256 * 4);
    float*  t1     = (float*)alloc(512UL * 256 * 4);
    float*  uu     = (float*)alloc(512UL * 256 * 4);

    // 1. agent projection: [64][512] f32  (8 col-tile blocks)
    gemm_k256<true, true, false, true><<<dim3(1, 8, 1), 256, 0, stream>>>(
        agent, 256, 0, W_agent, 256, b_agent, qa_out, 512, 0, 64, 512);
    // 2. score matrices M1|M2 + bias consts
    build_M2<<<128, 256, 0, stream>>>(W_qkv, b_qkv, qa_out, MS, cbias);
    // 3. streaming scores: S1T f32 + stage-1 partials; P2 = finalized stage-2 probs
    xproj2<<<1024, 256, 0, stream>>>(x, MS, cbias, S1T, P2, mpart, lpart);
    // 4. combine stage-1 stats
    s1_combine<<<8, 256, 0, stream>>>(mpart, lpart, m1, l1inv);
    // 5. y = attn1 @ x via MFMA
    pv_mfma2<<<dim3(32, 2, 8), 256, 0, stream>>>(S1T, x, m1, l1inv, y_part);
    // 6. reduce partials
    v1_reduce<<<dim3(64, 8), 64, 0, stream>>>(y_part, y_raw);
    // 7. folded chain: u = ((y@Wv^T+bv)@W1^T+b1)@W2^T+b2
    gemm_k256<true, true, false, true><<<dim3(4, 4, 1), 256, 0, stream>>>(
        y_raw, 256, 0, W_qkv + 512 * 256, 256, b_qkv + 512, t0, 256, 0, 512, 256);
    gemm_k256<true, true, false, true><<<dim3(4, 4, 1), 256, 0, stream>>>(
        t0, 256, 0, W_fc1, 256, b_fc1, t1, 256, 0, 512, 256);
    gemm_k256<true, true, false, true><<<dim3(4, 4, 1), 256, 0, stream>>>(
        t1, 256, 0, W_fc2, 256, b_fc2, uu, 256, 0, 512, 256);
    // 8. P2 copy + PV MFMA + residual + rmsnorm
    stage2_final<<<1024, 256, 0, stream>>>(P2, uu, x, nscale, out);
}

// Round 8
// 135.584 us; speedup vs baseline: 1.1026x; 1.1026x over previous
//
#include <hip/hip_runtime.h>
#include <hip/hip_bf16.h>

typedef __attribute__((ext_vector_type(4))) float f32x4;
typedef __attribute__((ext_vector_type(8))) short s16x8;
typedef __attribute__((ext_vector_type(4))) short s16x4;

__device__ __forceinline__ unsigned short f2bf(float f) {
    unsigned int u; __builtin_memcpy(&u, &f, 4);
    u += 0x7fffu + ((u >> 16) & 1u);
    return (unsigned short)(u >> 16);
}
__device__ __forceinline__ float bf2f(unsigned short h) {
    unsigned int u = ((unsigned int)h) << 16;
    float f; __builtin_memcpy(&f, &u, 4);
    return f;
}
__device__ __forceinline__ s16x8 pack8(f32x4 a, f32x4 b) {
    s16x8 r;
    r[0] = (short)f2bf(a[0]); r[1] = (short)f2bf(a[1]);
    r[2] = (short)f2bf(a[2]); r[3] = (short)f2bf(a[3]);
    r[4] = (short)f2bf(b[0]); r[5] = (short)f2bf(b[1]);
    r[6] = (short)f2bf(b[2]); r[7] = (short)f2bf(b[3]);
    return r;
}

// ---------------------------------------------------------------------------
// Generic C = A @ B^T (+bias) GEMM, K=256 — small matmuls (fc chain).
// Each block: one 64-col tile (blockIdx.y) of 128 rows (blockIdx.x).
// ---------------------------------------------------------------------------
template<bool AF32, bool BF32, bool OUTBF16, bool BIAS>
__global__ __launch_bounds__(256) void gemm_k256(
    const void* __restrict__ Ap, long sA, long bAstr,
    const void* __restrict__ Bp, long sB,
    const float* __restrict__ bias,
    void* __restrict__ Cp, long sC, long bCstr,
    int M, int N)
{
    __shared__ alignas(16) unsigned short As[128 * 256];
    __shared__ alignas(16) unsigned short Bs[64 * 256];
    const int tid = threadIdx.x;
    const int lane = tid & 63;
    const int w = tid >> 6;
    const int m0 = blockIdx.x * 128;
    const int nt = blockIdx.y;
    const int z = blockIdx.z;

    {
        const int kk = (tid & 31) * 8;
        #pragma unroll
        for (int j = 0; j < 16; ++j) {
            const int row = (tid >> 5) + j * 8;
            int rowg = m0 + row; if (rowg > M - 1) rowg = M - 1;
            s16x8 v;
            if constexpr (AF32) {
                const float* s = (const float*)Ap + (size_t)z * bAstr + (size_t)rowg * sA + kk;
                f32x4 f0 = *(const f32x4*)s;
                f32x4 f1 = *(const f32x4*)(s + 4);
                v = pack8(f0, f1);
            } else {
                const unsigned short* s = (const unsigned short*)Ap + (size_t)z * bAstr + (size_t)rowg * sA + kk;
                v = *(const s16x8*)s;
            }
            *(s16x8*)((char*)As + row * 512 + ((kk * 2) ^ ((row & 7) << 4))) = v;
        }
        #pragma unroll
        for (int j = 0; j < 8; ++j) {
            const int row = (tid >> 5) + j * 8;
            const int rowg = nt * 64 + row;
            s16x8 v;
            if constexpr (BF32) {
                const float* s = (const float*)Bp + (size_t)rowg * sB + kk;
                f32x4 f0 = *(const f32x4*)s;
                f32x4 f1 = *(const f32x4*)(s + 4);
                v = pack8(f0, f1);
            } else {
                const unsigned short* s = (const unsigned short*)Bp + (size_t)rowg * sB + kk;
                v = *(const s16x8*)s;
            }
            *(s16x8*)((char*)Bs + row * 512 + ((kk * 2) ^ ((row & 7) << 4))) = v;
        }
    }
    __syncthreads();

    f32x4 acc[2][4];
    const f32x4 zero = {0.f, 0.f, 0.f, 0.f};
    #pragma unroll
    for (int rf = 0; rf < 2; ++rf)
        #pragma unroll
        for (int cf = 0; cf < 4; ++cf)
            acc[rf][cf] = zero;

    #pragma unroll
    for (int ks = 0; ks < 8; ++ks) {
        const int kb = ks * 64 + ((lane >> 4) << 4);
        s16x8 areg[2], bfr[4];
        #pragma unroll
        for (int rf = 0; rf < 2; ++rf) {
            const int row = w * 32 + rf * 16 + (lane & 15);
            areg[rf] = *(const s16x8*)((const char*)As + row * 512 + (kb ^ ((row & 7) << 4)));
        }
        #pragma unroll
        for (int cf = 0; cf < 4; ++cf) {
            const int row = cf * 16 + (lane & 15);
            bfr[cf] = *(const s16x8*)((const char*)Bs + row * 512 + (kb ^ ((row & 7) << 4)));
        }
        #pragma unroll
        for (int rf = 0; rf < 2; ++rf)
            #pragma unroll
            for (int cf = 0; cf < 4; ++cf)
                acc[rf][cf] = __builtin_amdgcn_mfma_f32_16x16x32_bf16(
                    areg[rf], bfr[cf], acc[rf][cf], 0, 0, 0);
    }

    #pragma unroll
    for (int cf = 0; cf < 4; ++cf) {
        const int n = nt * 64 + cf * 16 + (lane & 15);
        const float bv = BIAS ? bias[n] : 0.f;
        #pragma unroll
        for (int rf = 0; rf < 2; ++rf) {
            #pragma unroll
            for (int r = 0; r < 4; ++r) {
                const int m = m0 + w * 32 + rf * 16 + ((lane >> 4) << 2) + r;
                if (m < M) {
                    const float v = acc[rf][cf][r] + bv;
                    const size_t co = (size_t)z * bCstr + (size_t)m * sC + n;
                    if constexpr (OUTBF16) ((unsigned short*)Cp)[co] = f2bf(v);
                    else                   ((float*)Cp)[co] = v;
                }
            }
        }
    }
}

// ---------------------------------------------------------------------------
// Build MS [128][256] bf16 + cbias[128], with the agent projection FUSED:
//   qa_s[t] = (agent[a] . W_agent[t'] + b_agent[t']) / 16,  t' = t or 256+t
//   rows  0..63 : M1[a] = qa_s @ W_k  (cbias = b_k . qa_s)   [stage-1]
//   rows 64..127: M2[a] = ka_s @ W_q  (cbias = b_q . ka_s)   [stage-2]
// ---------------------------------------------------------------------------
__global__ __launch_bounds__(256) void build_M2(
    const float* __restrict__ W_qkv, const float* __restrict__ b_qkv,
    const float* __restrict__ agent, const float* __restrict__ W_agent,
    const float* __restrict__ b_agent,
    unsigned short* __restrict__ MS, float* __restrict__ cbias)
{
    const int i = blockIdx.x;  // 0..127
    const int t = threadIdx.x;
    __shared__ float ag[256];
    __shared__ float qs[256];
    const int a = i & 63;
    const bool isS1 = (i < 64);
    ag[t] = agent[(size_t)a * 256 + t];
    __syncthreads();
    // fused agent projection for this block's (a, half)
    const int tp = isS1 ? t : 256 + t;
    {
        const float* wr = W_agent + (size_t)tp * 256;
        float q = 0.f;
        #pragma unroll 4
        for (int d = 0; d < 256; d += 4) {
            f32x4 wv = *(const f32x4*)(wr + d);
            q += ag[d] * wv[0] + ag[d + 1] * wv[1] + ag[d + 2] * wv[2] + ag[d + 3] * wv[3];
        }
        qs[t] = (q + b_agent[tp]) * 0.0625f;
    }
    __syncthreads();
    const float* W  = W_qkv + (isS1 ? 256 * 256 : 0);   // W_k : W_q
    const float* bb = b_qkv + (isS1 ? 256 : 0);
    float acc = 0.f, cb = 0.f;
    for (int dout = 0; dout < 256; ++dout) {
        const float q = qs[dout];
        acc += q * W[(size_t)dout * 256 + t];
        cb  += q * bb[dout];
    }
    MS[i * 256 + t] = f2bf(acc);
    if (t == 0) cbias[i] = cb;
}

// ---------------------------------------------------------------------------
// Streaming scores: per 64-token block computes S1T[n][a], S2[n][a] (f32)
// and stage-1 softmax partials.   (proven R6 version)
// ---------------------------------------------------------------------------
__global__ __launch_bounds__(256) void xproj2(
    const float* __restrict__ x,
    const unsigned short* __restrict__ MS,
    const float* __restrict__ cbias,
    float* __restrict__ S1T,
    float* __restrict__ S2,
    float* __restrict__ mpart, float* __restrict__ lpart)
{
    __shared__ alignas(16) unsigned short As[64 * 256];   // 32KB
    const int tid = threadIdx.x, lane = tid & 63, w = tid >> 6;
    const int lr = lane & 15, lq = lane >> 4;
    const long m0 = (long)blockIdx.x * 64;

    {
        const int k0 = (tid & 31) * 8;
        #pragma unroll
        for (int j = 0; j < 8; ++j) {
            const int row = (tid >> 5) + j * 8;
            const float* s = x + (m0 + row) * 256 + k0;
            f32x4 f0 = *(const f32x4*)s;
            f32x4 f1 = *(const f32x4*)(s + 4);
            *(s16x8*)((char*)As + row * 512 + ((k0 * 2) ^ ((row & 7) << 4))) = pack8(f0, f1);
        }
    }
    __syncthreads();

    f32x4 acc[4][2];
    const f32x4 zero = {0.f, 0.f, 0.f, 0.f};
    #pragma unroll
    for (int rf = 0; rf < 4; ++rf)
        #pragma unroll
        for (int j = 0; j < 2; ++j)
            acc[rf][j] = zero;

    #pragma unroll
    for (int ks = 0; ks < 8; ++ks) {
        const int kb = ks * 64 + lq * 16;
        s16x8 areg[4];
        #pragma unroll
        for (int rf = 0; rf < 4; ++rf) {
            const int row = rf * 16 + lr;
            areg[rf] = *(const s16x8*)((const char*)As + row * 512 + (kb ^ ((row & 7) << 4)));
        }
        s16x8 bfr[2];
        #pragma unroll
        for (int j = 0; j < 2; ++j) {
            const int msrow = j * 64 + w * 16 + lr;
            bfr[j] = *(const s16x8*)((const char*)MS + (size_t)msrow * 512 + kb);
        }
        #pragma unroll
        for (int rf = 0; rf < 4; ++rf)
            #pragma unroll
            for (int j = 0; j < 2; ++j)
                acc[rf][j] = __builtin_amdgcn_mfma_f32_16x16x32_bf16(
                    areg[rf], bfr[j], acc[rf][j], 0, 0, 0);
    }

    #pragma unroll
    for (int j = 0; j < 2; ++j) {
        const int a = w * 16 + lr;
        const float bv = cbias[j * 64 + a];
        float* dst = j ? S2 : S1T;
        float mx = -1e30f;
        #pragma unroll
        for (int rf = 0; rf < 4; ++rf)
            #pragma unroll
            for (int r = 0; r < 4; ++r) {
                const float v = acc[rf][j][r] + bv;
                dst[(m0 + rf * 16 + lq * 4 + r) * 64 + a] = v;
                mx = fmaxf(mx, v);
            }
        if (j == 0) {
            mx = fmaxf(mx, __shfl_xor(mx, 16));
            mx = fmaxf(mx, __shfl_xor(mx, 32));
            float sm = 0.f;
            #pragma unroll
            for (int rf = 0; rf < 4; ++rf)
                #pragma unroll
                for (int r = 0; r < 4; ++r)
                    sm += __expf(acc[rf][j][r] + bv - mx);
            sm += __shfl_xor(sm, 16);
            sm += __shfl_xor(sm, 32);
            if (lq == 0) {
                mpart[(size_t)blockIdx.x * 64 + a] = mx;
                lpart[(size_t)blockIdx.x * 64 + a] = sm;
            }
        }
    }
}

// ---------------------------------------------------------------------------
// y = attn1 @ x via MFMA (partials over 32 n-chunks of 256), with the
// stage-1 stat combine FUSED (reads mpart/lpart, reduces in scratch LDS
// overlaid on XT before XT is staged).
// ---------------------------------------------------------------------------
__global__ __launch_bounds__(256) void pv_mfma2(
    const float* __restrict__ S1T,
    const float* __restrict__ x,
    const float* __restrict__ mpart,
    const float* __restrict__ lpart,
    float* __restrict__ y_part)
{
    __shared__ alignas(16) unsigned short P_lds[64 * 128];   // [a][n] 16KB
    __shared__ alignas(16) unsigned short XT[128 * 136];     // [d][136n] (pad row)
    const int tid = threadIdx.x, lane = tid & 63, w = tid >> 6;
    const int lr = lane & 15, lq = lane >> 4;
    const int c = blockIdx.x, dh = blockIdx.y, b = blockIdx.z;
    const int a4 = (tid & 15) * 4;

    // ---- fused s1_combine: m1/l1inv for batch b, in scratch over XT ----
    f32x4 m4, l4;
    {
        float* scratch = (float*)XT;            // 1024 floats used (4KB < 34KB)
        const int a = tid & 63, s4 = tid >> 6;
        const size_t bb = (size_t)b * 128;
        float M = -1e30f;
        for (int cc = s4; cc < 128; cc += 4)
            M = fmaxf(M, mpart[(bb + cc) * 64 + a]);
        float L = 0.f;
        for (int cc = s4; cc < 128; cc += 4) {
            const size_t idx = (bb + cc) * 64 + a;
            L += lpart[idx] * __expf(mpart[idx] - M);
        }
        scratch[tid] = M;
        scratch[256 + tid] = L;
        __syncthreads();
        if (tid < 64) {
            float Mm = scratch[tid];
            #pragma unroll
            for (int ss = 1; ss < 4; ++ss) Mm = fmaxf(Mm, scratch[ss * 64 + tid]);
            float Ll = 0.f;
            #pragma unroll
            for (int ss = 0; ss < 4; ++ss)
                Ll += scratch[256 + ss * 64 + tid] * __expf(scratch[ss * 64 + tid] - Mm);
            scratch[512 + tid] = Mm;
            scratch[576 + tid] = 1.0f / Ll;
        }
        __syncthreads();
        #pragma unroll
        for (int j = 0; j < 4; ++j) {
            m4[j] = scratch[512 + a4 + j];
            l4[j] = scratch[576 + a4 + j];
        }
        __syncthreads();   // all reads done before XT staging overwrites
    }

    f32x4 acc[4][2];
    const f32x4 zero = {0.f, 0.f, 0.f, 0.f};
    #pragma unroll
    for (int rf = 0; rf < 4; ++rf)
        #pragma unroll
        for (int cf = 0; cf < 2; ++cf)
            acc[rf][cf] = zero;

    for (int kt = 0; kt < 2; ++kt) {
        const size_t ng0 = (size_t)b * 8192 + c * 256 + kt * 128;
        #pragma unroll
        for (int pass = 0; pass < 4; ++pass) {
            const int np = 2 * (tid >> 4) + pass * 32;
            const float* s = S1T + (ng0 + np) * 64 + a4;
            f32x4 s0 = *(const f32x4*)s;
            f32x4 s1 = *(const f32x4*)(s + 64);
            #pragma unroll
            for (int j = 0; j < 4; ++j) {
                const int a = a4 + j;
                const float p0 = __expf(s0[j] - m4[j]) * l4[j];
                const float p1 = __expf(s1[j] - m4[j]) * l4[j];
                const unsigned int pk = (unsigned int)f2bf(p0) | ((unsigned int)f2bf(p1) << 16);
                *(unsigned int*)((char*)P_lds + a * 256 + ((np * 2) ^ (((a >> 1) & 7) << 4))) = pk;
            }
        }
        {
            const int nh = tid >> 2;
            const int dq = tid & 3;
            const float* xbase = x + (ng0 + 2 * nh) * 256 + dh * 128;
            #pragma unroll
            for (int pass = 0; pass < 8; ++pass) {
                const int dl0 = pass * 16 + dq * 4;
                f32x4 xa = *(const f32x4*)(xbase + dl0);
                f32x4 xb = *(const f32x4*)(xbase + 256 + dl0);
                #pragma unroll
                for (int jj = 0; jj < 4; ++jj) {
                    const unsigned int pk = (unsigned int)f2bf(xa[jj]) | ((unsigned int)f2bf(xb[jj]) << 16);
                    *(unsigned int*)((char*)XT + (dl0 + jj) * 272 + nh * 4) = pk;
                }
            }
        }
        __syncthreads();
        #pragma unroll
        for (int ks = 0; ks < 4; ++ks) {
            const int kbn = ks * 64 + lq * 16;
            s16x8 af[4], bfv[2];
            #pragma unroll
            for (int rf = 0; rf < 4; ++rf) {
                const int row = rf * 16 + lr;
                af[rf] = *(const s16x8*)((const char*)P_lds + row * 256 + (kbn ^ (((row >> 1) & 7) << 4)));
            }
            #pragma unroll
            for (int cf = 0; cf < 2; ++cf) {
                const int dl = w * 32 + cf * 16 + lr;
                bfv[cf] = *(const s16x8*)((const char*)XT + dl * 272 + kbn);
            }
            #pragma unroll
            for (int rf = 0; rf < 4; ++rf)
                #pragma unroll
                for (int cf = 0; cf < 2; ++cf)
                    acc[rf][cf] = __builtin_amdgcn_mfma_f32_16x16x32_bf16(
                        af[rf], bfv[cf], acc[rf][cf], 0, 0, 0);
        }
        __syncthreads();
    }
    #pragma unroll
    for (int rf = 0; rf < 4; ++rf)
        #pragma unroll
        for (int cf = 0; cf < 2; ++cf)
            #pragma unroll
            for (int r = 0; r < 4; ++r) {
                const int a = rf * 16 + lq * 4 + r;
                const int d = dh * 128 + w * 32 + cf * 16 + lr;
                y_part[(((size_t)b * 32 + c) * 64 + a) * 256 + d] = acc[rf][cf][r];
            }
}

// reduce partials -> y bf16 (feeds the bf16 GEMM chain directly)
__global__ void v1_reduce(const float* __restrict__ y_part,
                          unsigned short* __restrict__ y_rawb)
{
    const int a = blockIdx.x, b = blockIdx.y, t = threadIdx.x;  // 64 thr
    f32x4 s = {0.f, 0.f, 0.f, 0.f};
    for (int c = 0; c < 32; ++c)
        s += *(const f32x4*)&y_part[(((size_t)b * 32 + c) * 64 + a) * 256 + t * 4];
    s16x4 pk;
    #pragma unroll
    for (int j = 0; j < 4; ++j) pk[j] = (short)f2bf(s[j]);
    *(s16x4*)&y_rawb[((size_t)b * 64 + a) * 256 + t * 4] = pk;
}

// ---------------------------------------------------------------------------
// Stage-2 fused: parallel softmax(64) + PV via MFMA (A = uT rows d, B = P
// rows n -> thread holds 4 CONSECUTIVE d per token) + residual + RMSNorm.
// (proven R6 version)
// ---------------------------------------------------------------------------
__global__ __launch_bounds__(256) void stage2_final(const float* __restrict__ S2,
                                                    const float* __restrict__ uu,
                                                    const float* __restrict__ x,
                                                    const float* __restrict__ nscale,
                                                    float* __restrict__ out)
{
    __shared__ alignas(16) unsigned short uT[256 * 64];  // [d][a] pitch 128B, swz
    __shared__ alignas(16) unsigned short P[64 * 64];    // [n][a] pitch 128B, swz
    __shared__ float ssq[4][64];
    const int tid = threadIdx.x, lane = tid & 63, w = tid >> 6;
    const int lr = lane & 15, lq = lane >> 4;
    const int b = blockIdx.x >> 7;
    const long n0 = (long)blockIdx.x * 64;

    {
        const int pr = tid >> 3;      // a-pair 0..31
        const int sub = tid & 7;
        const float* u0 = uu + ((size_t)b * 64 + 2 * pr) * 256;
        #pragma unroll
        for (int pass = 0; pass < 8; ++pass) {
            const int d0 = pass * 32 + sub * 4;
            f32x4 ua = *(const f32x4*)(u0 + d0);
            f32x4 ub = *(const f32x4*)(u0 + 256 + d0);
            #pragma unroll
            for (int jj = 0; jj < 4; ++jj) {
                const int d = d0 + jj;
                const unsigned int pk = (unsigned int)f2bf(ua[jj]) | ((unsigned int)f2bf(ub[jj]) << 16);
                *(unsigned int*)((char*)uT + d * 128 + ((pr * 4) ^ ((d & 7) << 4))) = pk;
            }
        }
    }
    {
        const int t = lane >> 2, q = lane & 3;
        const int nl = w * 16 + t;
        const float* srow = S2 + (n0 + nl) * 64 + q * 16;
        f32x4 sv[4];
        #pragma unroll
        for (int j = 0; j < 4; ++j) sv[j] = *(const f32x4*)(srow + j * 4);
        float mx = -1e30f;
        #pragma unroll
        for (int j = 0; j < 4; ++j)
            #pragma unroll
            for (int e = 0; e < 4; ++e) mx = fmaxf(mx, sv[j][e]);
        mx = fmaxf(mx, __shfl_xor(mx, 1));
        mx = fmaxf(mx, __shfl_xor(mx, 2));
        float p[16];
        float sm = 0.f;
        #pragma unroll
        for (int j = 0; j < 4; ++j)
            #pragma unroll
            for (int e = 0; e < 4; ++e) {
                p[j * 4 + e] = __expf(sv[j][e] - mx);
                sm += p[j * 4 + e];
            }
        sm += __shfl_xor(sm, 1);
        sm += __shfl_xor(sm, 2);
        const float rs = 1.f / sm;
        s16x8 o0, o1;
        #pragma unroll
        for (int e = 0; e < 8; ++e) o0[e] = (short)f2bf(p[e] * rs);
        #pragma unroll
        for (int e = 0; e < 8; ++e) o1[e] = (short)f2bf(p[8 + e] * rs);
        const int swz = (nl & 7) << 4;
        *(s16x8*)((char*)P + nl * 128 + ((q * 32) ^ swz)) = o0;
        *(s16x8*)((char*)P + nl * 128 + ((q * 32 + 16) ^ swz)) = o1;
    }
    __syncthreads();

    f32x4 acc[4][4];
    const f32x4 zero = {0.f, 0.f, 0.f, 0.f};
    #pragma unroll
    for (int rf = 0; rf < 4; ++rf)
        #pragma unroll
        for (int cf = 0; cf < 4; ++cf)
            acc[rf][cf] = zero;
    #pragma unroll
    for (int ks = 0; ks < 2; ++ks) {
        const int kb = ks * 64 + lq * 16;
        s16x8 af[4], bfv[4];
        #pragma unroll
        for (int rf = 0; rf < 4; ++rf) {
            const int dR = w * 64 + rf * 16 + lr;
            af[rf] = *(const s16x8*)((const char*)uT + dR * 128 + (kb ^ ((dR & 7) << 4)));
        }
        #pragma unroll
        for (int cf = 0; cf < 4; ++cf) {
            const int nR = cf * 16 + lr;
            bfv[cf] = *(const s16x8*)((const char*)P + nR * 128 + (kb ^ ((nR & 7) << 4)));
        }
        #pragma unroll
        for (int rf = 0; rf < 4; ++rf)
            #pragma unroll
            for (int cf = 0; cf < 4; ++cf)
                acc[rf][cf] = __builtin_amdgcn_mfma_f32_16x16x32_bf16(
                    af[rf], bfv[cf], acc[rf][cf], 0, 0, 0);
    }

    float part[4] = {0.f, 0.f, 0.f, 0.f};
    #pragma unroll
    for (int cf = 0; cf < 4; ++cf) {
        const long n = n0 + cf * 16 + lr;
        #pragma unroll
        for (int rf = 0; rf < 4; ++rf) {
            const int d0 = w * 64 + rf * 16 + lq * 4;
            const f32x4 xr = *(const f32x4*)&x[n * 256 + d0];
            acc[rf][cf] += xr;
            part[cf] += acc[rf][cf][0] * acc[rf][cf][0] + acc[rf][cf][1] * acc[rf][cf][1]
                      + acc[rf][cf][2] * acc[rf][cf][2] + acc[rf][cf][3] * acc[rf][cf][3];
        }
    }
    #pragma unroll
    for (int cf = 0; cf < 4; ++cf) {
        float s = part[cf];
        s += __shfl_xor(s, 16);
        s += __shfl_xor(s, 32);
        if (lq == 0) ssq[w][cf * 16 + lr] = s;
    }
    __syncthreads();

    #pragma unroll
    for (int cf = 0; cf < 4; ++cf) {
        const int tokl = cf * 16 + lr;
        const float tot = ssq[0][tokl] + ssq[1][tokl] + ssq[2][tokl] + ssq[3][tokl];
        const float inv = 1.f / (sqrtf(tot) * 0.0625f + 1e-8f);
        const long n = n0 + tokl;
        #pragma unroll
        for (int rf = 0; rf < 4; ++rf) {
            const int d0 = w * 64 + rf * 16 + lq * 4;
            const f32x4 sc4 = *(const f32x4*)&nscale[d0];
            f32x4 o = sc4 * acc[rf][cf] * inv;
            *(f32x4*)&out[n * 256 + d0] = o;
        }
    }
}

// ---------------------------------------------------------------------------
extern "C" void kernel_launch(void* const* d_in, const int* in_sizes, int n_in,
                              void* d_out, int out_size, void* d_ws, size_t ws_size,
                              hipStream_t stream)
{
    const float* agent   = (const float*)d_in[0];
    const float* x       = (const float*)d_in[1];
    const float* W_qkv   = (const float*)d_in[2];
    const float* b_qkv   = (const float*)d_in[3];
    const float* W_agent = (const float*)d_in[4];
    const float* b_agent = (const float*)d_in[5];
    const float* W_fc1   = (const float*)d_in[6];
    const float* b_fc1   = (const float*)d_in[7];
    const float* W_fc2   = (const float*)d_in[8];
    const float* b_fc2   = (const float*)d_in[9];
    const float* nscale  = (const float*)d_in[10];
    float* out = (float*)d_out;

    char* wsp = (char*)d_ws;
    size_t off = 0;
    auto alloc = [&](size_t n) { void* p = wsp + off; off += (n + 255) & ~(size_t)255; return p; };

    unsigned short* MS = (unsigned short*)alloc(128UL * 256 * 2);
    float*  cbias  = (float*)alloc(128UL * 4);
    float*  S1T    = (float*)alloc(65536UL * 64 * 4);   // [n][a]
    float*  S2     = (float*)alloc(65536UL * 64 * 4);   // [n][a]
    float*  mpart  = (float*)alloc(1024UL * 64 * 4);
    float*  lpart  = (float*)alloc(1024UL * 64 * 4);
    float*  y_part = (float*)alloc(8UL * 32 * 64 * 256 * 4);
    unsigned short* y_rawb = (unsigned short*)alloc(512UL * 256 * 2);
    unsigned short* t0b    = (unsigned short*)alloc(512UL * 256 * 2);
    unsigned short* t1b    = (unsigned short*)alloc(512UL * 256 * 2);
    float*  uu     = (float*)alloc(512UL * 256 * 4);

    // 1. score matrices M1|M2 + bias consts (agent projection fused inside)
    build_M2<<<128, 256, 0, stream>>>(W_qkv, b_qkv, agent, W_agent, b_agent, MS, cbias);
    // 2. streaming scores S1T, S2 + stage-1 softmax partials
    xproj2<<<1024, 256, 0, stream>>>(x, MS, cbias, S1T, S2, mpart, lpart);
    // 3. y = attn1 @ x via MFMA (stage-1 stat combine fused inside)
    pv_mfma2<<<dim3(32, 2, 8), 256, 0, stream>>>(S1T, x, mpart, lpart, y_part);
    // 4. reduce partials -> bf16
    v1_reduce<<<dim3(64, 8), 64, 0, stream>>>(y_part, y_rawb);
    // 5. folded chain: u = ((y@Wv^T+bv)@W1^T+b1)@W2^T+b2  (bf16 A throughout)
    gemm_k256<false, true, true, true><<<dim3(4, 4, 1), 256, 0, stream>>>(
        y_rawb, 256, 0, W_qkv + 512 * 256, 256, b_qkv + 512, t0b, 256, 0, 512, 256);
    gemm_k256<false, true, true, true><<<dim3(4, 4, 1), 256, 0, stream>>>(
        t0b, 256, 0, W_fc1, 256, b_fc1, t1b, 256, 0, 512, 256);
    gemm_k256<false, true, false, true><<<dim3(4, 4, 1), 256, 0, stream>>>(
        t1b, 256, 0, W_fc2, 256, b_fc2, uu, 256, 0, 512, 256);
    // 6. parallel softmax + PV MFMA + residual + rmsnorm
    stage2_final<<<1024, 256, 0, stream>>>(S2, uu, x, nscale, out);
}